// Round 4
// baseline (1169.049 us; speedup 1.0000x reference)
//
#include <hip/hip_runtime.h>

#define GG 4
#define TT 2048
#define EE 8
#define DD 1024
#define CC 2048

static constexpr long long GTEC = (long long)GG * TT * EE * CC;     // 134217728
static constexpr long long FILL4 = 2 * GTEC / 4;                    // 67108864 float4
#define NBLK 16384                 // total K1 blocks; every 8th is a probs block
#define NFILL 14336                // fill blocks = NBLK - 2048
// ws layout (floats): [0, 8192) per-token z partials | [8192, 8192+65536) probs
#define WS_ZTOK 0
#define WS_PROBS 8192

// ---------------------------------------------------------------------------
// K1: fused zero-fill + router probs. LDS-FREE (round 2 showed 32KB LDS in
// this kernel costs ~47us of fill occupancy). NUMERICS WARNING: the probs
// dot product MUST keep the scalar stride-64 fmaf order from rounds 1-2 —
// round 3's float4-horizontal reorder flipped a top-k boundary selection
// (absmax=1.0). Accumulation order is part of the correctness contract here.
// ---------------------------------------------------------------------------
__global__ __launch_bounds__(256) void k1_fill_probs(
    const float* __restrict__ x, const float* __restrict__ W,
    const float* __restrict__ bias, float* __restrict__ ws,
    float* __restrict__ out)
{
    const int b = blockIdx.x;
    if ((b & 7) == 7) {
        // ---- probs block: 4 waves, one token each ----
        const int pid  = b >> 3;               // 0..2047
        const int wave = threadIdx.x >> 6;
        const int lane = threadIdx.x & 63;
        const int token = pid * 4 + wave;      // 0..8191
        const float* xr = x + (long long)token * DD;

        float acc[EE];
#pragma unroll
        for (int e = 0; e < EE; ++e) acc[e] = 0.f;

        // EXACT round-1/2 ordering: k = lane, lane+64, ... (coalesced loads)
#pragma unroll 4
        for (int k = lane; k < DD; k += 64) {
            float xv = xr[k];
#pragma unroll
            for (int e = 0; e < EE; ++e)
                acc[e] = fmaf(xv, W[e * DD + k], acc[e]);
        }

        // butterfly reduce across the 64-lane wave (same order as rounds 1-2)
#pragma unroll
        for (int off = 32; off > 0; off >>= 1) {
#pragma unroll
            for (int e = 0; e < EE; ++e)
                acc[e] += __shfl_xor(acc[e], off, 64);
        }
#pragma unroll
        for (int e = 0; e < EE; ++e) acc[e] += bias[e];

        float m = acc[0];
#pragma unroll
        for (int e = 1; e < EE; ++e) m = fmaxf(m, acc[e]);
        float s = 0.f;
#pragma unroll
        for (int e = 0; e < EE; ++e) s += expf(acc[e] - m);
        float lse = m + logf(s);

        if (lane < EE)
            ws[WS_PROBS + (long long)token * EE + lane] = expf(acc[lane] - lse);
        if (lane == 0) {
            float zs = 0.f;
#pragma unroll
            for (int e = 0; e < EE; ++e) {
                float d = acc[e] - lse;
                zs = fmaf(d, d, zs);
            }
            ws[WS_ZTOK + token] = zs;
        }
    } else {
        // ---- fill block: zero 2*GTEC floats as float4, grid-stride ----
        const int fid = b - ((b + 1) >> 3);    // 0..NFILL-1
        float4* o4 = (float4*)out;
        const float4 z = make_float4(0.f, 0.f, 0.f, 0.f);
        for (long long i = (long long)fid * 256 + threadIdx.x; i < FILL4;
             i += (long long)NFILL * 256)
            o4[i] = z;
    }
}

// ---------------------------------------------------------------------------
// K2: blocks 0..255 -> rank-select+scatter for (g,e,chunk of 256 tokens);
//     block 256     -> z-loss reduction over 8192 per-token partials.
// rank(t) = #{ j : (p_j > p_t) or (p_j == p_t and j < t) }  == slot in the
// stable descending top-k; tokens with rank < cap are selected.
// ---------------------------------------------------------------------------
__global__ __launch_bounds__(256) void k2_rank_scatter(
    const float* __restrict__ ws, float* __restrict__ out)
{
    __shared__ float sp[TT];     // 8 KB
    const int b = blockIdx.x;
    if (b < 256) {
        const int g = b >> 6;
        const int e = (b >> 3) & 7;
        const int chunk = b & 7;
        const int caps[EE] = {512, 512, 256, 256, 128, 128, 128, 128};
        const int cap = caps[e];

        for (int i = threadIdx.x; i < TT; i += 256)
            sp[i] = ws[WS_PROBS + ((long long)g * TT + i) * EE + e];
        __syncthreads();

        const int t = chunk * 256 + threadIdx.x;
        const float p = sp[t];
        int rank = 0;
        const float4* sp4 = (const float4*)sp;
#pragma unroll 4
        for (int j4 = 0; j4 < TT / 4; ++j4) {
            float4 v = sp4[j4];
            int j = j4 * 4;
            rank += (v.x > p) || (v.x == p && (j + 0) < t);
            rank += (v.y > p) || (v.y == p && (j + 1) < t);
            rank += (v.z > p) || (v.z == p && (j + 2) < t);
            rank += (v.w > p) || (v.w == p && (j + 3) < t);
        }
        if (rank < cap) {
            long long base = (((long long)g * TT + t) * EE + e) * CC + rank;
            out[base] = 1.0f;         // dispatch_mask
            out[GTEC + base] = p;     // combine_array
        }
    } else {
        // ---- z-loss: reduce 8192 per-token partials ----
        float s = 0.f;
        for (int i = threadIdx.x; i < 8192; i += 256)
            s += ws[WS_ZTOK + i];
#pragma unroll
        for (int off = 32; off > 0; off >>= 1) s += __shfl_xor(s, off, 64);
        __shared__ float red[4];
        if ((threadIdx.x & 63) == 0) red[threadIdx.x >> 6] = s;
        __syncthreads();
        if (threadIdx.x == 0)
            out[2 * GTEC] = ((red[0] + red[1]) + (red[2] + red[3])) *
                            (1.0f / ((float)GG * TT * EE));
    }
}

extern "C" void kernel_launch(void* const* d_in, const int* in_sizes, int n_in,
                              void* d_out, int out_size, void* d_ws, size_t ws_size,
                              hipStream_t stream) {
    const float* x    = (const float*)d_in[0];
    const float* W    = (const float*)d_in[1];
    const float* bias = (const float*)d_in[2];
    float* out = (float*)d_out;
    float* ws  = (float*)d_ws;

    k1_fill_probs<<<NBLK, 256, 0, stream>>>(x, W, bias, ws, out);
    k2_rank_scatter<<<257, 256, 0, stream>>>(ws, out);
}

// Round 5
// 1093.102 us; speedup vs baseline: 1.0695x; 1.0695x over previous
//
#include <hip/hip_runtime.h>

#define GG 4
#define TT 2048
#define EE 8
#define DD 1024
#define CC 2048

static constexpr long long GTEC = (long long)GG * TT * EE * CC; // 134217728
// ws layout (floats): [0, 8192) per-token z partials | [8192, 8192+65536) probs
#define WS_ZTOK 0
#define WS_PROBS 8192

// ---------------------------------------------------------------------------
// STRUCTURE NOTE (rounds 2 & 4 post-mortems): fusing the probs compute into
// the 1.07 GB zero-fill stream regressed BOTH times (LDS variant +47us, L2
// variant +80us) — compute blocks interleaved in the fill grid disturb the
// write stream / add TCC read traffic. Serialized memset + small kernels is
// the measured winner. Do not re-fuse.
//
// NUMERICS NOTE (round 3 post-mortem): the logits dot product MUST keep this
// exact scalar stride-64 fmaf order + this butterfly order. Reordering flips
// top-k boundary selections (absmax=1.0). Accumulation order is contractual.
// ---------------------------------------------------------------------------
__global__ __launch_bounds__(256) void router_probs_kernel(
    const float* __restrict__ x, const float* __restrict__ W,
    const float* __restrict__ bias, float* __restrict__ ws)
{
    __shared__ float sW[EE * DD];   // 32 KB
    for (int i = threadIdx.x; i < EE * DD; i += 256) sW[i] = W[i];
    __syncthreads();

    const int wave = threadIdx.x >> 6;
    const int lane = threadIdx.x & 63;
    const int token = blockIdx.x * 4 + wave;   // grid = GG*TT/4, exact
    const float* xr = x + (long long)token * DD;

    float acc[EE];
#pragma unroll
    for (int e = 0; e < EE; ++e) acc[e] = 0.f;

#pragma unroll 4
    for (int k = lane; k < DD; k += 64) {
        float xv = xr[k];
#pragma unroll
        for (int e = 0; e < EE; ++e)
            acc[e] = fmaf(xv, sW[e * DD + k], acc[e]);
    }

    // butterfly reduce across the 64-lane wave
#pragma unroll
    for (int off = 32; off > 0; off >>= 1) {
#pragma unroll
        for (int e = 0; e < EE; ++e)
            acc[e] += __shfl_xor(acc[e], off, 64);
    }

#pragma unroll
    for (int e = 0; e < EE; ++e) acc[e] += bias[e];

    float m = acc[0];
#pragma unroll
    for (int e = 1; e < EE; ++e) m = fmaxf(m, acc[e]);
    float s = 0.f;
#pragma unroll
    for (int e = 0; e < EE; ++e) s += expf(acc[e] - m);
    float lse = m + logf(s);

    if (lane < EE)
        ws[WS_PROBS + (long long)token * EE + lane] = expf(acc[lane] - lse);

    if (lane == 0) {
        float zs = 0.f;
#pragma unroll
        for (int e = 0; e < EE; ++e) {
            float d = acc[e] - lse;
            zs = fmaf(d, d, zs);
        }
        ws[WS_ZTOK + token] = zs;
    }
}

// ---------------------------------------------------------------------------
// K2 (verbatim from round 4, passed): blocks 0..255 -> rank-select+scatter
// for (g,e,chunk of 256 tokens); block 256 -> z-loss reduction.
// rank(t) = #{ j : (p_j > p_t) or (p_j == p_t and j < t) }  == slot in the
// stable descending top-k; tokens with rank < cap are selected.
// ---------------------------------------------------------------------------
__global__ __launch_bounds__(256) void k2_rank_scatter(
    const float* __restrict__ ws, float* __restrict__ out)
{
    __shared__ float sp[TT];     // 8 KB
    const int b = blockIdx.x;
    if (b < 256) {
        const int g = b >> 6;
        const int e = (b >> 3) & 7;
        const int chunk = b & 7;
        const int caps[EE] = {512, 512, 256, 256, 128, 128, 128, 128};
        const int cap = caps[e];

        for (int i = threadIdx.x; i < TT; i += 256)
            sp[i] = ws[WS_PROBS + ((long long)g * TT + i) * EE + e];
        __syncthreads();

        const int t = chunk * 256 + threadIdx.x;
        const float p = sp[t];
        int rank = 0;
        const float4* sp4 = (const float4*)sp;
#pragma unroll 4
        for (int j4 = 0; j4 < TT / 4; ++j4) {
            float4 v = sp4[j4];
            int j = j4 * 4;
            rank += (v.x > p) || (v.x == p && (j + 0) < t);
            rank += (v.y > p) || (v.y == p && (j + 1) < t);
            rank += (v.z > p) || (v.z == p && (j + 2) < t);
            rank += (v.w > p) || (v.w == p && (j + 3) < t);
        }
        if (rank < cap) {
            long long base = (((long long)g * TT + t) * EE + e) * CC + rank;
            out[base] = 1.0f;         // dispatch_mask
            out[GTEC + base] = p;     // combine_array
        }
    } else {
        // ---- z-loss: reduce 8192 per-token partials ----
        float s = 0.f;
        for (int i = threadIdx.x; i < 8192; i += 256)
            s += ws[WS_ZTOK + i];
#pragma unroll
        for (int off = 32; off > 0; off >>= 1) s += __shfl_xor(s, off, 64);
        __shared__ float red[4];
        if ((threadIdx.x & 63) == 0) red[threadIdx.x >> 6] = s;
        __syncthreads();
        if (threadIdx.x == 0)
            out[2 * GTEC] = ((red[0] + red[1]) + (red[2] + red[3])) *
                            (1.0f / ((float)GG * TT * EE));
    }
}

extern "C" void kernel_launch(void* const* d_in, const int* in_sizes, int n_in,
                              void* d_out, int out_size, void* d_ws, size_t ws_size,
                              hipStream_t stream) {
    const float* x    = (const float*)d_in[0];
    const float* W    = (const float*)d_in[1];
    const float* bias = (const float*)d_in[2];
    float* out = (float*)d_out;
    float* ws  = (float*)d_ws;

    // zero both output arrays + z_loss slot (d_out is poisoned each launch);
    // runtime fill runs at the measured ~6.25 TB/s ceiling — don't hand-roll.
    hipMemsetAsync(d_out, 0, (size_t)out_size * sizeof(float), stream);

    router_probs_kernel<<<GG * TT / 4, 256, 0, stream>>>(x, W, bias, ws);
    k2_rank_scatter<<<257, 256, 0, stream>>>(ws, out);
}